// Round 9
// baseline (329.974 us; speedup 1.0000x reference)
//
#include <hip/hip_runtime.h>

// PostNormBoth: T=256-step recurrence, B=512 chains, H=256.
// R10: ONE barrier per step. The LN-stats LDS round-trip is taken off the
// critical chain algebraically:
//   v(t+1) = vP(t+1) + rstd(t)*C(t+1)*vQ~ - mu(t)*rstd(t)*C(t+1)*gm
//     vP(t+1) = inp(t+1) + cs*ctxB(t+1) + C(t+1)*bt   (stats-free)
//     vQ(t+1) = gm .* yt(t)                           (stats-free)
//   y(t+1) = W.vP + [rstd*C]*(W.vQ) + [-mu*rstd*C]*yG,  yG = W.gm (precomp)
// so stats(t) are consumed as SCALARS after the t+1 MFMA -> the s_red
// exchange hides under the MFMA phase. MFMA cols now carry 4 real vectors
// (row x {P,Q}, 4x replicated) -> still 16 MFMAs, 8 ds_reads per wave.
// Partner value (other vector, same i) via one DPP quad_perm (lane^2).
// s_v and s_red are ping-pong buffered -> single barrier suffices.
// Window is updated one step deferred (hn(t-1) applied at iter t; retire
// slot t-3; 6-reg window t-3..t+2 entering iter t).

#define TT 256

typedef __bf16 bf16x8 __attribute__((ext_vector_type(8)));
typedef float  f32x4  __attribute__((ext_vector_type(4)));

__device__ __forceinline__ float fast_tanh(float x) {
    float e = __expf(2.f * x);
    return 1.f - __fdividef(2.f, e + 1.f);
}

// v += dpp(v); old=0 + bound_ctrl so masked lanes add 0.
template<int CTRL, int RM>
__device__ __forceinline__ float dpp_add(float v) {
    int t = __builtin_amdgcn_update_dpp(0, __float_as_int(v), CTRL, RM, 0xf, true);
    return v + __int_as_float(t);
}
// v += swizzle(v) with compile-time BitMode pattern.
template<int IMM>
__device__ __forceinline__ float swz_add(float v) {
    int t = __builtin_amdgcn_ds_swizzle(__float_as_int(v), IMM);
    return v + __int_as_float(t);
}
// pure lane^2 permute (quad_perm [2,3,0,1])
__device__ __forceinline__ float dpp_xor2_mov(float v) {
    int t = __builtin_amdgcn_update_dpp(0, __float_as_int(v), 0x4E, 0xf, 0xf, true);
    return __int_as_float(t);
}

// ---- dynamic LDS layout (bytes) ----
// s_mem  [2][64][256] f32 :      0  (131072)
// s_x    [2][256]     f32 : 131072  (2048)
// s_v    [2buf][4][272] bf16 : 133120 (4352)   stride 272: rows on banks 0/8/16/24
// s_red1 [2buf][2][8] f32 : 137472  (128)
// s_red2 [2buf][2][8] f32 : 137600  (128)
// s_wt   [64][8]      f32 : 137728  (2048)
// s_oacc [20]         f32 : 139776  (80)
#define SMEM_BYTES 139856

__global__ __launch_bounds__(512, 2)
void postnorm_kernel(const float* __restrict__ x,
                     const float* __restrict__ W_embed,
                     const float* __restrict__ b_embed,
                     const float* __restrict__ W_update,
                     const float* __restrict__ b_update,
                     const float* __restrict__ gamma,
                     const float* __restrict__ beta,
                     const float* __restrict__ W_out,
                     const float* __restrict__ b_out,
                     const float* __restrict__ ctx_s,
                     float* __restrict__ out)
{
    extern __shared__ __align__(16) char smem[];
    float*  s_mem  = (float*)(smem);
    float*  s_x    = (float*)(smem + 131072);
    __bf16* s_v    = (__bf16*)(smem + 133120);   // [buf][vr][272]
    float*  s_red1 = (float*)(smem + 137472);    // [buf][row][8]
    float*  s_red2 = (float*)(smem + 137600);
    float*  s_wt   = (float*)(smem + 137728);
    float*  s_oacc = (float*)(smem + 139776);

    const int tid  = threadIdx.x;
    const int wave = tid >> 6;       // wave w owns W rows [32w,32w+32)
    const int lane = tid & 63;
    const int bn   = lane & 15;      // MFMA col: row=bit0, pq=bit1, rep=bits2-3
    const int quad = lane >> 4;
    const int r0   = blockIdx.x * 2;

    const int row  = bn & 1;
    const int pq   = (bn >> 1) & 1;  // 0 = P-column, 1 = Q-column
    const int rep  = bn >> 2;        // 4x replica index -> supplies (mt, rsel-hi)
    const int mt   = rep >> 1;
    const int rsel = (rep & 1) * 2 + pq;
    const int i_own = wave * 32 + mt * 16 + quad * 4 + rsel;  // bijective w/ (row)

    // ---- init ----
    {   f32x4 z = {0.f, 0.f, 0.f, 0.f};
        f32x4* p = (f32x4*)s_mem;
        #pragma unroll
        for (int k = 0; k < 16; ++k) p[tid + k * 512] = z;
    }
    s_x[tid] = x[(r0 + (tid >> 8)) * TT + (tid & 255)];
    if (tid < 64) ((float*)(smem + 137472))[tid] = 0.f;   // zero both s_red bufs
    if (tid < 20) s_oacc[tid] = 0.f;

    // weight table: pointer is t&63; row padded to 8 floats
    if (tid < 64) {
        float wv[5]; float ssum = 0.f;
        #pragma unroll
        for (int k = 0; k < 5; ++k) {
            int idx = (tid + k - 2) & 63;
            float d = (float)idx - (float)tid;
            wv[k] = expf(-(d * d) * 0.125f);   // TAU=8
            ssum += wv[k];
        }
        #pragma unroll
        for (int k = 0; k < 5; ++k) s_wt[tid * 8 + k] = wv[k] / ssum;
    }

    // per-owned-i params
    const float we  = W_embed[i_own];
    const float be  = b_embed[i_own];
    const float bu  = b_update[i_own];
    const float gm  = gamma[i_own];
    const float btt = beta[i_own];
    const float csv = 1.f / (1.f + expf(-ctx_s[0]));

    // ---- W_update -> bf16 MFMA A-fragments resident in VGPRs ----
    bf16x8 wfa[2][8];
    #pragma unroll
    for (int mtt = 0; mtt < 2; ++mtt) {
        #pragma unroll
        for (int kt = 0; kt < 8; ++kt) {
            const float* wp = W_update + (wave * 32 + mtt * 16 + bn) * 256
                                       + kt * 32 + quad * 8;
            f32x4 a = *(const f32x4*)wp;
            f32x4 bb = *(const f32x4*)(wp + 4);
            bf16x8 f;
            f[0] = (__bf16)a[0];  f[1] = (__bf16)a[1];
            f[2] = (__bf16)a[2];  f[3] = (__bf16)a[3];
            f[4] = (__bf16)bb[0]; f[5] = (__bf16)bb[1];
            f[6] = (__bf16)bb[2]; f[7] = (__bf16)bb[3];
            wfa[mtt][kt] = f;
        }
    }

    // ---- prologue A: fill buf0 all 4 v-rows with gm -> compute yG = W.gm ----
    s_v[row * 272 + i_own]       = (__bf16)gm;
    s_v[(row + 2) * 272 + i_own] = (__bf16)gm;
    __syncthreads();

    float yG;
    {
        const __bf16* vsrc = s_v + (bn & 3) * 272 + quad * 8;
        f32x4 a0a = {0,0,0,0}, a0b = {0,0,0,0}, a1a = {0,0,0,0}, a1b = {0,0,0,0};
        #pragma unroll
        for (int kt = 0; kt < 4; ++kt) {
            bf16x8 bfr0 = *(const bf16x8*)(vsrc + kt * 32);
            bf16x8 bfr1 = *(const bf16x8*)(vsrc + (kt + 4) * 32);
            a0a = __builtin_amdgcn_mfma_f32_16x16x32_bf16(wfa[0][kt],     bfr0, a0a, 0, 0, 0);
            a1a = __builtin_amdgcn_mfma_f32_16x16x32_bf16(wfa[1][kt],     bfr0, a1a, 0, 0, 0);
            a0b = __builtin_amdgcn_mfma_f32_16x16x32_bf16(wfa[0][kt + 4], bfr1, a0b, 0, 0, 0);
            a1b = __builtin_amdgcn_mfma_f32_16x16x32_bf16(wfa[1][kt + 4], bfr1, a1b, 0, 0, 0);
        }
        f32x4 y0 = a0a + a0b, y1 = a1a + a1b;
        f32x4 ym = mt ? y1 : y0;
        float pl = (rep & 1) ? ym[2] : ym[0];
        float ph = (rep & 1) ? ym[3] : ym[1];
        yG = pq ? ph : pl;   // ym[rsel]
    }
    __syncthreads();   // MFMA reads done before buf0 is overwritten

    // ---- prologue B: v(0) into buf0: vP = tanh(x0*we+be), vQ = 0 ----
    {
        float inp0 = fast_tanh(s_x[row * 256] * we + be);
        s_v[row * 272 + i_own]       = (__bf16)inp0;
        s_v[(row + 2) * 272 + i_own] = (__bf16)0.f;
    }

    // carried state
    float wm0 = s_wt[63*8+0], wm1 = s_wt[63*8+1], wm2 = s_wt[63*8+2],
          wm3 = s_wt[63*8+3], wm4 = s_wt[63*8+4];                    // w(t-1)
    float wc0 = s_wt[0], wc1 = s_wt[1], wc2 = s_wt[2],
          wc3 = s_wt[3], wc4 = s_wt[4];                              // w(t)
    float wp0 = s_wt[8+0], wp1 = s_wt[8+1], wp2 = s_wt[8+2],
          wp3 = s_wt[8+3], wp4 = s_wt[8+4];                          // w(t+1)
    float u0 = 0.f, u1 = 0.f, u2 = 0.f, u3 = 0.f, u4 = 0.f, u5 = 0.f;
    float yt_prev = 0.f, C_cur = 1.f;
    float* mcol = s_mem + (row << 14) + i_own;
    float nf = mcol[3 << 8];                 // admit slot 3 (zero-init)
    float xn = s_x[row * 256 + 1];           // x(1)
    float hn = 0.f;
    __syncthreads();   // v(0) visible; loop reads buf0 at t=0

    #pragma unroll 1
    for (int t = 0; t < TT; ++t) {
        const int rb = t & 1, wb = rb ^ 1;

        // stats(t-1) reads (buf wb) -- overlap with MFMA below
        const float* rp1 = s_red1 + (wb * 2 + row) * 8;
        const float* rp2 = s_red2 + (wb * 2 + row) * 8;
        f32x4 r1a = *(const f32x4*)rp1, r1b = *(const f32x4*)(rp1 + 4);
        f32x4 r2a = *(const f32x4*)rp2, r2b = *(const f32x4*)(rp2 + 4);

        // --- MFMA: y-parts for all 4 (row,pq) vectors, buf rb ---
        const __bf16* vsrc = s_v + (rb * 4 + (bn & 3)) * 272 + quad * 8;
        f32x4 a0a = {0,0,0,0}, a0b = {0,0,0,0}, a1a = {0,0,0,0}, a1b = {0,0,0,0};
        #pragma unroll
        for (int kt = 0; kt < 4; ++kt) {
            bf16x8 bfr0 = *(const bf16x8*)(vsrc + kt * 32);
            bf16x8 bfr1 = *(const bf16x8*)(vsrc + (kt + 4) * 32);
            a0a = __builtin_amdgcn_mfma_f32_16x16x32_bf16(wfa[0][kt],     bfr0, a0a, 0, 0, 0);
            a1a = __builtin_amdgcn_mfma_f32_16x16x32_bf16(wfa[1][kt],     bfr0, a1a, 0, 0, 0);
            a0b = __builtin_amdgcn_mfma_f32_16x16x32_bf16(wfa[0][kt + 4], bfr1, a0b, 0, 0, 0);
            a1b = __builtin_amdgcn_mfma_f32_16x16x32_bf16(wfa[1][kt + 4], bfr1, a1b, 0, 0, 0);
        }

        // --- stats(t-1) finalize (scalars) ---
        float S1 = ((r1a[0]+r1a[1])+(r1a[2]+r1a[3])) + ((r1b[0]+r1b[1])+(r1b[2]+r1b[3]));
        float S2 = ((r2a[0]+r2a[1])+(r2a[2]+r2a[3])) + ((r2b[0]+r2b[1])+(r2b[2]+r2b[3]));
        float mu   = S1 * (1.f / 256.f);
        float var  = S2 * (1.f / 256.f) - mu * mu;
        float rstd = rsqrtf(var + 1e-5f);
        const float m0 = (t == 0) ? 0.f : 1.f;     // kill phantom hn(-1)/stats(-1)
        float aC = rstd * C_cur * m0;              // alpha = rstd*C(t)
        float bC = -mu * aC;                       // beta  = -mu*rstd*C(t)

        // --- extract own + partner y, combine ---
        f32x4 y0 = a0a + a0b, y1 = a1a + a1b;
        f32x4 ym = mt ? y1 : y0;
        float pl = (rep & 1) ? ym[2] : ym[0];
        float ph = (rep & 1) ? ym[3] : ym[1];
        float own  = pq ? ph : pl;                 // ym[rsel]   : own vector
        float give = pq ? pl : ph;                 // ym[rsel^1] : partner's i
        float recv = dpp_xor2_mov(give);           // other vector, my i
        float yP = pq ? recv : own;
        float yQ = pq ? own  : recv;
        float y  = yP + aC * yQ + bC * yG;

        // --- tanh + stats(t) partial reduce (row-parity preserved) ---
        float yt = fast_tanh(y + bu);
        float s1 = yt, s2 = yt * yt;
        s1 = dpp_add<0x4E, 0xf>(s1);  s2 = dpp_add<0x4E, 0xf>(s2);  // xor2
        s1 = swz_add<0x101F>(s1);     s2 = swz_add<0x101F>(s2);     // xor4
        s1 = swz_add<0x201F>(s1);     s2 = swz_add<0x201F>(s2);     // xor8
        s1 = swz_add<0x401F>(s1);     s2 = swz_add<0x401F>(s2);     // xor16
        s1 += __shfl_xor(s1, 32, 64); s2 += __shfl_xor(s2, 32, 64); // xor32
        if (lane < 2) {   // lane == row for lanes 0,1
            s_red1[(rb * 2 + lane) * 8 + wave] = s1;
            s_red2[(rb * 2 + lane) * 8 + wave] = s2;
        }

        // --- deferred window: apply hn(t-1) with w(t-1); retire slot t-3 ---
        hn = m0 * ((yt_prev - mu) * rstd * gm + btt);
        u0 += wm0 * hn; u1 += wm1 * hn; u2 += wm2 * hn;
        u3 += wm3 * hn; u4 += wm4 * hn;            // slots t-3..t+1
        mcol[((t - 3) & 63) << 8] = u0;            // retire (complete)
        u0 = u1; u1 = u2; u2 = u3; u3 = u4; u4 = u5; u5 = nf;  // admit t+3
        // now u0..u5 = slots t-2..t+3, contributions through hn(t-1)

        // --- ctxB(t+1), C(t+1), vP/vQ(t+1) ---
        float ctxB = ((wp0 * u1 + wp1 * u2) + (wp2 * u3 + wp3 * u4)) + wp4 * u5;
        float wd   = (wp0 * wc1 + wp1 * wc2) + (wp2 * wc3 + wp3 * wc4);
        float Cn   = 1.f + csv * wd;
        float inp  = fast_tanh(xn * we + be);
        float vP   = inp + csv * ctxB + Cn * btt;
        float vQ   = gm * yt;
        __bf16* svw = s_v + wb * 1088;
        svw[row * 272 + i_own]       = (__bf16)vP;
        svw[(row + 2) * 272 + i_own] = (__bf16)vQ;

        // --- carry + prefetch ---
        C_cur = Cn;  yt_prev = yt;
        wm0 = wc0; wm1 = wc1; wm2 = wc2; wm3 = wc3; wm4 = wc4;
        wc0 = wp0; wc1 = wp1; wc2 = wp2; wc3 = wp3; wc4 = wp4;
        {   const float* wrow = s_wt + ((t + 2) & 63) * 8;
            f32x4 wn = *(const f32x4*)wrow;
            wp0 = wn[0]; wp1 = wn[1]; wp2 = wn[2]; wp3 = wn[3]; wp4 = wrow[4];
        }
        nf = mcol[((t + 4) & 63) << 8];   // admit for next iter (same-thread col)
        xn = s_x[row * 256 + ((t + 2) & 255)];
        __syncthreads();
    }

    // --- epilogue: finalize hn(TT-1) with stats(TT-1) (in red buf 1) ---
    {
        const float* rp1 = s_red1 + (1 * 2 + row) * 8;
        const float* rp2 = s_red2 + (1 * 2 + row) * 8;
        f32x4 r1a = *(const f32x4*)rp1, r1b = *(const f32x4*)(rp1 + 4);
        f32x4 r2a = *(const f32x4*)rp2, r2b = *(const f32x4*)(rp2 + 4);
        float S1 = ((r1a[0]+r1a[1])+(r1a[2]+r1a[3])) + ((r1b[0]+r1b[1])+(r1b[2]+r1b[3]));
        float S2 = ((r2a[0]+r2a[1])+(r2a[2]+r2a[3])) + ((r2b[0]+r2b[1])+(r2b[2]+r2b[3]));
        float mu   = S1 * (1.f / 256.f);
        float var  = S2 * (1.f / 256.f) - mu * mu;
        float rstd = rsqrtf(var + 1e-5f);
        float hfin = (yt_prev - mu) * rstd * gm + btt;
        s_x[row * 256 + i_own] = hfin;     // stage to tid-order (x no longer needed)
    }
    __syncthreads();
    {
        const int n = tid >> 8, i = tid & 255;
        float h = s_x[tid];
        #pragma unroll
        for (int o = 0; o < 10; ++o) {
            float p = h * W_out[o * 256 + i];
            #pragma unroll
            for (int m = 32; m >= 1; m >>= 1) p += __shfl_xor(p, m, 64);
            if (lane == 0) atomicAdd(&s_oacc[n * 10 + o], p);
        }
    }
    __syncthreads();
    if (tid < 20) {
        int nn = tid / 10, o = tid % 10;
        out[(r0 + nn) * 10 + o] = s_oacc[tid] + b_out[o];
    }
}

extern "C" void kernel_launch(void* const* d_in, const int* in_sizes, int n_in,
                              void* d_out, int out_size, void* d_ws, size_t ws_size,
                              hipStream_t stream) {
    const float* x    = (const float*)d_in[0];
    const float* W_e  = (const float*)d_in[1];
    const float* b_e  = (const float*)d_in[2];
    const float* W_u  = (const float*)d_in[3];
    const float* b_u  = (const float*)d_in[4];
    const float* gmm  = (const float*)d_in[5];
    const float* bta  = (const float*)d_in[6];
    const float* W_o  = (const float*)d_in[7];
    const float* b_o  = (const float*)d_in[8];
    const float* cst  = (const float*)d_in[9];
    float* out = (float*)d_out;

    (void)hipFuncSetAttribute(reinterpret_cast<const void*>(postnorm_kernel),
                              hipFuncAttributeMaxDynamicSharedMemorySize,
                              SMEM_BYTES);

    postnorm_kernel<<<dim3(256), dim3(512), SMEM_BYTES, stream>>>(
        x, W_e, b_e, W_u, b_u, gmm, bta, W_o, b_o, cst, out);
}

// Round 10
// 313.832 us; speedup vs baseline: 1.0514x; 1.0514x over previous
//
#include <hip/hip_runtime.h>

// PostNormBoth: T=256-step recurrence, B=512 chains, H=256.
// R11 = R9 (best: 281.6us) + DS-FREE LN REDUCE.
// Chain audit: step ~2650cyc contains ~7 serial LDS-hw hops @~120cyc
// (ds_read v, 3x ds_swizzle + 1x shfl IN THE REDUCE, s_red read, v write->
// read). The reduce's 4 DS hops (~480cyc) are replaced with VALU-latency
// ops: xor2 (DPP quad_perm) + row_ror:4 + row_ror:8 (DPP rotations;
// rotation-accumulate covers {0,4,8,12} within each 16-lane row, parity
// bit0=row preserved) + v_permlane32_swap_b32 (gfx950 VALU) for bit5.
// Bit4 folds into the s_red exchange: 4 partials/wave (lanes 0,1,16,17 =
// parity x bit4), finalize reads 16 floats/row (4x f32x4) instead of 8.
// Everything else is R9 verbatim.

#define TT 256

typedef __bf16 bf16x8 __attribute__((ext_vector_type(8)));
typedef float  f32x4  __attribute__((ext_vector_type(4)));

__device__ __forceinline__ float fast_tanh(float x) {
    float e = __expf(2.f * x);
    return 1.f - __fdividef(2.f, e + 1.f);
}

// v += dpp(v); old=0 + bound_ctrl so masked lanes add 0.
template<int CTRL, int RM>
__device__ __forceinline__ float dpp_add(float v) {
    int t = __builtin_amdgcn_update_dpp(0, __float_as_int(v), CTRL, RM, 0xf, true);
    return v + __int_as_float(t);
}
// v += v[lane^32] via v_permlane32_swap (VALU, no LDS hardware).
// With a=b=v: a' = {v[0:31], v[0:31]}, b' = {v[32:63], v[32:63]} -> a'+b'
// gives every lane v[i&31]+v[i|32].
__device__ __forceinline__ float swap32_add(float v) {
    float a = v, b = v;
    asm("v_permlane32_swap_b32 %0, %1" : "+v"(a), "+v"(b));
    return a + b;
}

// ---- dynamic LDS layout (bytes) ----
// s_mem  [2][64][256] f32 :      0  (131072)
// s_x    [2][256]     f32 : 131072  (2048)
// s_v    [2][288]     bf16: 133120  (1152)
// s_red1 [2][16]      f32 : 134272  (128)
// s_red2 [2][16]      f32 : 134400  (128)
// s_wt   [64][8]      f32 : 134528  (2048)
// s_oacc [20]         f32 : 136576  (80)
#define SMEM_BYTES 136656

__global__ __launch_bounds__(512, 2)
void postnorm_kernel(const float* __restrict__ x,
                     const float* __restrict__ W_embed,
                     const float* __restrict__ b_embed,
                     const float* __restrict__ W_update,
                     const float* __restrict__ b_update,
                     const float* __restrict__ gamma,
                     const float* __restrict__ beta,
                     const float* __restrict__ W_out,
                     const float* __restrict__ b_out,
                     const float* __restrict__ ctx_s,
                     float* __restrict__ out)
{
    extern __shared__ __align__(16) char smem[];
    float*  s_mem  = (float*)(smem);
    float*  s_x    = (float*)(smem + 131072);
    __bf16* s_v    = (__bf16*)(smem + 133120);
    float*  s_red1 = (float*)(smem + 134272);   // [row][wave*2 + bit4]
    float*  s_red2 = (float*)(smem + 134400);
    float*  s_wt   = (float*)(smem + 134528);
    float*  s_oacc = (float*)(smem + 136576);

    const int tid  = threadIdx.x;
    const int wave = tid >> 6;       // wave w owns W rows [32w,32w+32)
    const int lane = tid & 63;
    const int bn   = lane & 15;      // MFMA col
    const int quad = lane >> 4;
    const int r0   = blockIdx.x * 2;

    // ownership: this lane's accumulators hold y[i_own] for row `row`
    const int b     = bn >> 1;
    const int row   = bn & 1;
    const int i_own = wave * 32 + (b >> 2) * 16 + quad * 4 + (b & 3);

    // ---- init ----
    {   f32x4 z = {0.f, 0.f, 0.f, 0.f};
        f32x4* p = (f32x4*)s_mem;
        #pragma unroll
        for (int k = 0; k < 16; ++k) p[tid + k * 512] = z;
    }
    s_x[tid] = x[(r0 + (tid >> 8)) * TT + (tid & 255)];
    if (tid < 64) ((float*)(smem + 134272))[tid] = 0.f;   // zero s_red1+s_red2
    if (tid < 20) s_oacc[tid] = 0.f;

    // weight table: pointer is t&63; row padded to 8 floats
    if (tid < 64) {
        float wv[5]; float ssum = 0.f;
        #pragma unroll
        for (int k = 0; k < 5; ++k) {
            int idx = (tid + k - 2) & 63;            // wrapped index
            float d = (float)idx - (float)tid;       // delta AFTER wrap
            wv[k] = expf(-(d * d) * 0.125f);         // TAU=8
            ssum += wv[k];
        }
        #pragma unroll
        for (int k = 0; k < 5; ++k) s_wt[tid * 8 + k] = wv[k] / ssum;
    }

    // per-owned-i params
    const float we  = W_embed[i_own];
    const float be  = b_embed[i_own];
    const float bu  = b_update[i_own];
    const float gm  = gamma[i_own];
    const float btt = beta[i_own];
    const float csv = 1.f / (1.f + expf(-ctx_s[0]));

    // ---- W_update -> bf16 MFMA A-fragments resident in VGPRs ----
    bf16x8 wfa[2][8];
    #pragma unroll
    for (int mt = 0; mt < 2; ++mt) {
        #pragma unroll
        for (int kt = 0; kt < 8; ++kt) {
            const float* wp = W_update + (wave * 32 + mt * 16 + bn) * 256
                                       + kt * 32 + quad * 8;
            f32x4 a = *(const f32x4*)wp;
            f32x4 bb = *(const f32x4*)(wp + 4);
            bf16x8 f;
            f[0] = (__bf16)a[0];  f[1] = (__bf16)a[1];
            f[2] = (__bf16)a[2];  f[3] = (__bf16)a[3];
            f[4] = (__bf16)bb[0]; f[5] = (__bf16)bb[1];
            f[6] = (__bf16)bb[2]; f[7] = (__bf16)bb[3];
            wfa[mt][kt] = f;
        }
    }

    __syncthreads();
    {   // v(t=0): memory==0, h==0 -> v = inp (one write per owned (row,i))
        float inp0 = fast_tanh(s_x[row * 256] * we + be);
        s_v[row * 288 + i_own] = (__bf16)inp0;
    }

    // attention weights for pointer 0 + step-0 prefetches
    float wt0, wt1, wt2, wt3, wt4;
    {   f32x4 wv = *(const f32x4*)(s_wt);
        wt0 = wv[0]; wt1 = wv[1]; wt2 = wv[2]; wt3 = wv[3]; wt4 = s_wt[4];
    }
    f32x4 nw  = *(const f32x4*)(s_wt + 8);       // weights for pointer 1
    float nw4 = s_wt[8 + 4];
    float xn  = s_x[row * 256 + 1];              // x[t+1] for own row
    float nf  = 0.f;                             // admit slot 3 (zero-init)
    __syncthreads();

    float hn = 0.f;
    // register window: slots (t-2..t+2) mod 64 of memory column (row,i_own)
    float w0 = 0.f, w1 = 0.f, w2 = 0.f, w3 = 0.f, w4 = 0.f;
    float* mcol = s_mem + (row << 14) + i_own;
    // broadcast B-frag source; row stride 288 bf16 keeps rows bank-disjoint
    const __bf16* vsrc = s_v + row * 288 + quad * 8;

    #pragma unroll 1
    for (int t = 0; t < TT; ++t) {
        // input embed for v(t+1): independent of this step -> hides under P1
        float inp = fast_tanh(xn * we + be);

        // --- P1: y = W . v via MFMA; D col bn carries row bn&1 ---
        f32x4 a0a = {0,0,0,0}, a0b = {0,0,0,0}, a1a = {0,0,0,0}, a1b = {0,0,0,0};
        #pragma unroll
        for (int kt = 0; kt < 4; ++kt) {
            bf16x8 bfr0 = *(const bf16x8*)(vsrc + kt * 32);
            bf16x8 bfr1 = *(const bf16x8*)(vsrc + (kt + 4) * 32);
            a0a = __builtin_amdgcn_mfma_f32_16x16x32_bf16(wfa[0][kt],     bfr0, a0a, 0, 0, 0);
            a1a = __builtin_amdgcn_mfma_f32_16x16x32_bf16(wfa[1][kt],     bfr0, a1a, 0, 0, 0);
            a0b = __builtin_amdgcn_mfma_f32_16x16x32_bf16(wfa[0][kt + 4], bfr1, a0b, 0, 0, 0);
            a1b = __builtin_amdgcn_mfma_f32_16x16x32_bf16(wfa[1][kt + 4], bfr1, a1b, 0, 0, 0);
        }

        // --- select owned y from regs (no LDS): (mt,r) = (b>>2, b&3) ---
        f32x4 y0 = a0a + a0b, y1 = a1a + a1b;
        f32x4 ym = (b & 4) ? y1 : y0;
        float yA = (b & 2) ? ym[2] : ym[0];
        float yB = (b & 2) ? ym[3] : ym[1];
        float ysel = (b & 1) ? yB : yA;

        // --- P2: tanh + LN stats; DS-FREE reduce over bits{1,2,3,5} ---
        float yt = fast_tanh(ysel + bu);
        float s1 = yt, s2 = yt * yt;
        s1 = dpp_add<0x4E,  0xf>(s1);  s2 = dpp_add<0x4E,  0xf>(s2);  // xor2  (bit1)
        s1 = dpp_add<0x124, 0xf>(s1);  s2 = dpp_add<0x124, 0xf>(s2);  // ror:4 (bits2,3 pt1)
        s1 = dpp_add<0x128, 0xf>(s1);  s2 = dpp_add<0x128, 0xf>(s2);  // ror:8 (bits2,3 pt2)
        s1 = swap32_add(s1);           s2 = swap32_add(s2);           // bit5 (VALU permlane)
        // lanes 0,1,16,17 hold the 4 distinct partials (parity x bit4)
        if ((lane & 46) == 0) {
            const int b4 = (lane >> 4) & 1;      // row = lane&1
            s_red1[(lane & 1) * 16 + wave * 2 + b4] = s1;
            s_red2[(lane & 1) * 16 + wave * 2 + b4] = s2;
        }
        __syncthreads();   // [1] partials visible (also fences vsrc reads)

        // --- P3: LN finalize + window + v ---
        const float* rp1 = s_red1 + row * 16;
        const float* rp2 = s_red2 + row * 16;
        f32x4 r1a = *(const f32x4*)rp1,       r1b = *(const f32x4*)(rp1 + 4);
        f32x4 r1c = *(const f32x4*)(rp1 + 8), r1d = *(const f32x4*)(rp1 + 12);
        f32x4 r2a = *(const f32x4*)rp2,       r2b = *(const f32x4*)(rp2 + 4);
        f32x4 r2c = *(const f32x4*)(rp2 + 8), r2d = *(const f32x4*)(rp2 + 12);
        float S1 = (((r1a[0]+r1a[1]) + (r1a[2]+r1a[3])) + ((r1b[0]+r1b[1]) + (r1b[2]+r1b[3])))
                 + (((r1c[0]+r1c[1]) + (r1c[2]+r1c[3])) + ((r1d[0]+r1d[1]) + (r1d[2]+r1d[3])));
        float S2 = (((r2a[0]+r2a[1]) + (r2a[2]+r2a[3])) + ((r2b[0]+r2b[1]) + (r2b[2]+r2b[3])))
                 + (((r2c[0]+r2c[1]) + (r2c[2]+r2c[3])) + ((r2d[0]+r2d[1]) + (r2d[2]+r2d[3])));
        float mu   = S1 * (1.f / 256.f);
        float var  = S2 * (1.f / 256.f) - mu * mu;
        float rstd = rsqrtf(var + 1e-5f);
        hn = (yt - mu) * rstd * gm + btt;

        // scatter with pointer-t weights (positional: w0 = slot t-2)
        w0 += wt0 * hn; w1 += wt1 * hn; w2 += wt2 * hn;
        w3 += wt3 * hn; w4 += wt4 * hn;

        // slide window: retire slot t-2, admit slot t+3 (prefetched)
        mcol[((t - 2) & 63) << 8] = w0;
        w0 = w1; w1 = w2; w2 = w3; w3 = w4; w4 = nf;
        float ctx = ((nw[0] * w0 + nw[1] * w1) + (nw[2] * w2 + nw[3] * w3))
                  + nw4 * w4;
        float v = inp + csv * ctx + hn;
        s_v[row * 288 + i_own] = (__bf16)v;
        wt0 = nw[0]; wt1 = nw[1]; wt2 = nw[2]; wt3 = nw[3]; wt4 = nw4;

        // prefetch next step's P3 inputs; loop-end barrier covers latency.
        // mcol slot (t+4)&63 is same-thread-only -> no cross-thread hazard.
        nf  = mcol[((t + 4) & 63) << 8];
        {   const float* wp = s_wt + ((t + 2) & 63) * 8;
            nw  = *(const f32x4*)wp;
            nw4 = wp[4];
        }
        xn  = s_x[row * 256 + ((t + 2) & 255)];
        __syncthreads();   // [2] v visible
    }

    // --- epilogue: stage hn into s_x (reuse) to restore tid-order ---
    s_x[row * 256 + i_own] = hn;
    __syncthreads();
    {
        const int n = tid >> 8, i = tid & 255;
        float h = s_x[tid];
        #pragma unroll
        for (int o = 0; o < 10; ++o) {
            float p = h * W_out[o * 256 + i];
            #pragma unroll
            for (int m = 32; m >= 1; m >>= 1) p += __shfl_xor(p, m, 64);
            if (lane == 0) atomicAdd(&s_oacc[n * 10 + o], p);
        }
    }
    __syncthreads();
    if (tid < 20) {
        int nn = tid / 10, o = tid % 10;
        out[(r0 + nn) * 10 + o] = s_oacc[tid] + b_out[o];
    }
}

extern "C" void kernel_launch(void* const* d_in, const int* in_sizes, int n_in,
                              void* d_out, int out_size, void* d_ws, size_t ws_size,
                              hipStream_t stream) {
    const float* x    = (const float*)d_in[0];
    const float* W_e  = (const float*)d_in[1];
    const float* b_e  = (const float*)d_in[2];
    const float* W_u  = (const float*)d_in[3];
    const float* b_u  = (const float*)d_in[4];
    const float* gmm  = (const float*)d_in[5];
    const float* bta  = (const float*)d_in[6];
    const float* W_o  = (const float*)d_in[7];
    const float* b_o  = (const float*)d_in[8];
    const float* cst  = (const float*)d_in[9];
    float* out = (float*)d_out;

    (void)hipFuncSetAttribute(reinterpret_cast<const void*>(postnorm_kernel),
                              hipFuncAttributeMaxDynamicSharedMemorySize,
                              SMEM_BYTES);

    postnorm_kernel<<<dim3(256), dim3(512), SMEM_BYTES, stream>>>(
        x, W_e, b_e, W_u, b_u, gmm, bta, W_o, b_o, cst, out);
}

// Round 11
// 295.682 us; speedup vs baseline: 1.1160x; 1.0614x over previous
//
#include <hip/hip_runtime.h>

// PostNormBoth: T=256-step recurrence, B=512 chains, H=256.
// R12 = R9/R11 chassis + post-barrier chain collapsed to ~10 ops:
//  (1) LDS-atomic stats: all-VALU reduce (xor2 DPP, ror4, ror8,
//      permlane16_swap, permlane32_swap -> every lane holds its row's full
//      wave partial), then 4 lanes/wave do one masked atomicAdd into
//      ping-pong s_acc[buf][row][{S1,S2}]. Post-barrier finalize = ONE
//      b64 read + 0 adds (was 4-8 ds_read_b128 + ~30 adds in every lane).
//  (2) ctx decomposition (R10's validated piece, without its MFMA bloat):
//      v(t+1) = base + coef*hn, base/coef computed PRE-barrier from the
//      pre-scatter window; post-hn chain = 1 fma + cvt + ds_write.
//      Window scatter/slide/retire moved off the critical path.
//  (3) exp2-folded tanh (premultiplied 2*log2e) saves a mul per tanh.
// Rationale: R10 (+40 chain-VALU = +18us) and R6 (+4x lane VALU = +40us)
// vs null results for barrier/DS-latency cuts => step time is priced in
// per-lane dependent ops (~5cyc each); this removes ~45 of them.

#define TT 256

typedef __bf16 bf16x8 __attribute__((ext_vector_type(8)));
typedef float  f32x4  __attribute__((ext_vector_type(4)));
typedef float  f32x2  __attribute__((ext_vector_type(2)));

#define C2 2.8853900817779268f   // 2*log2(e)

// tanh(x) with pre-scaled arg u = 2*log2e*x: 1 - 2/(exp2(u)+1)
__device__ __forceinline__ float tanh_pre(float u) {
    float e = exp2f(u);
    return 1.f - __fdividef(2.f, e + 1.f);
}

// v += dpp(v); old=0 + bound_ctrl so masked lanes add 0.
template<int CTRL, int RM>
__device__ __forceinline__ float dpp_add(float v) {
    int t = __builtin_amdgcn_update_dpp(0, __float_as_int(v), CTRL, RM, 0xf, true);
    return v + __int_as_float(t);
}
// v += v[lane^32] via v_permlane32_swap (VALU, validated R11).
__device__ __forceinline__ float swap32_add(float v) {
    float a = v, b = v;
    asm("v_permlane32_swap_b32 %0, %1" : "+v"(a), "+v"(b));
    return a + b;
}
// v += v[lane^16] via v_permlane16_swap (gfx950 VALU, same encoding family).
__device__ __forceinline__ float swap16_add(float v) {
    float a = v, b = v;
    asm("v_permlane16_swap_b32 %0, %1" : "+v"(a), "+v"(b));
    return a + b;
}

// ---- dynamic LDS layout (bytes) ----
// s_mem [2][64][256] f32 :      0  (131072)
// s_x   [2][256]     f32 : 131072  (2048)
// s_v   [2][288]     bf16: 133120  (1152)
// s_acc [2][2][2]    f32 : 134272  (32)    [buf][row][{S1,S2}]
// s_wt  [64][8]      f32 : 134304  (2048)
// s_oacc[20]         f32 : 136352  (80)
#define SMEM_BYTES 136432

__global__ __launch_bounds__(512, 2)
void postnorm_kernel(const float* __restrict__ x,
                     const float* __restrict__ W_embed,
                     const float* __restrict__ b_embed,
                     const float* __restrict__ W_update,
                     const float* __restrict__ b_update,
                     const float* __restrict__ gamma,
                     const float* __restrict__ beta,
                     const float* __restrict__ W_out,
                     const float* __restrict__ b_out,
                     const float* __restrict__ ctx_s,
                     float* __restrict__ out)
{
    extern __shared__ __align__(16) char smem[];
    float*  s_mem  = (float*)(smem);
    float*  s_x    = (float*)(smem + 131072);
    __bf16* s_v    = (__bf16*)(smem + 133120);
    float*  s_acc  = (float*)(smem + 134272);
    float*  s_wt   = (float*)(smem + 134304);
    float*  s_oacc = (float*)(smem + 136352);

    const int tid  = threadIdx.x;
    const int wave = tid >> 6;       // wave w owns W rows [32w,32w+32)
    const int lane = tid & 63;
    const int bn   = lane & 15;      // MFMA col
    const int quad = lane >> 4;
    const int r0   = blockIdx.x * 2;

    // ownership: this lane's accumulators hold y[i_own] for row `row`
    const int b     = bn >> 1;
    const int row   = bn & 1;
    const int i_own = wave * 32 + (b >> 2) * 16 + quad * 4 + (b & 3);

    // ---- init ----
    {   f32x4 z = {0.f, 0.f, 0.f, 0.f};
        f32x4* p = (f32x4*)s_mem;
        #pragma unroll
        for (int k = 0; k < 16; ++k) p[tid + k * 512] = z;
    }
    s_x[tid] = x[(r0 + (tid >> 8)) * TT + (tid & 255)];
    if (tid < 8)  s_acc[tid] = 0.f;
    if (tid < 20) s_oacc[tid] = 0.f;

    // weight table: pointer is t&63; row padded to 8 floats
    if (tid < 64) {
        float wv[5]; float ssum = 0.f;
        #pragma unroll
        for (int k = 0; k < 5; ++k) {
            int idx = (tid + k - 2) & 63;            // wrapped index
            float d = (float)idx - (float)tid;       // delta AFTER wrap
            wv[k] = expf(-(d * d) * 0.125f);         // TAU=8
            ssum += wv[k];
        }
        #pragma unroll
        for (int k = 0; k < 5; ++k) s_wt[tid * 8 + k] = wv[k] / ssum;
    }

    // per-owned-i params (embed/bias pre-scaled for exp2 tanh)
    const float we2 = W_embed[i_own] * C2;
    const float be2 = b_embed[i_own] * C2;
    const float bu2 = b_update[i_own] * C2;
    const float gm  = gamma[i_own];
    const float btt = beta[i_own];
    const float csv = 1.f / (1.f + expf(-ctx_s[0]));

    // ---- W_update -> bf16 MFMA A-fragments resident in VGPRs ----
    bf16x8 wfa[2][8];
    #pragma unroll
    for (int mt = 0; mt < 2; ++mt) {
        #pragma unroll
        for (int kt = 0; kt < 8; ++kt) {
            const float* wp = W_update + (wave * 32 + mt * 16 + bn) * 256
                                       + kt * 32 + quad * 8;
            f32x4 a = *(const f32x4*)wp;
            f32x4 bb = *(const f32x4*)(wp + 4);
            bf16x8 f;
            f[0] = (__bf16)a[0];  f[1] = (__bf16)a[1];
            f[2] = (__bf16)a[2];  f[3] = (__bf16)a[3];
            f[4] = (__bf16)bb[0]; f[5] = (__bf16)bb[1];
            f[6] = (__bf16)bb[2]; f[7] = (__bf16)bb[3];
            wfa[mt][kt] = f;
        }
    }

    __syncthreads();
    {   // v(t=0): memory==0, h==0 -> v = inp (one write per owned (row,i))
        float inp0 = tanh_pre(fmaf(s_x[row * 256], we2, be2));
        s_v[row * 288 + i_own] = (__bf16)inp0;
    }

    // attention weights for pointer 0 + step-0 prefetches
    float wt0, wt1, wt2, wt3, wt4;
    {   f32x4 wv = *(const f32x4*)(s_wt);
        wt0 = wv[0]; wt1 = wv[1]; wt2 = wv[2]; wt3 = wv[3]; wt4 = s_wt[4];
    }
    f32x4 nw  = *(const f32x4*)(s_wt + 8);       // weights for pointer t+1
    float nw4 = s_wt[8 + 4];
    float xn  = s_x[row * 256 + 1];              // x[t+1] for own row
    float nf  = 0.f;                             // admit slot 3 (zero-init)
    __syncthreads();

    float hn = 0.f;
    // register window: slots (t-2..t+2) mod 64 of memory column (row,i_own)
    float w0 = 0.f, w1 = 0.f, w2 = 0.f, w3 = 0.f, w4 = 0.f;
    float* mcol = s_mem + (row << 14) + i_own;
    // broadcast B-frag source; row stride 288 bf16 keeps rows bank-disjoint
    const __bf16* vsrc = s_v + row * 288 + quad * 8;

    #pragma unroll 1
    for (int t = 0; t < TT; ++t) {
        const int rb = t & 1, wb = rb ^ 1;

        // --- pre-barrier: everything not depending on stats(t) ---
        // v(t+1) = base + coef*hn(t):
        //   ctxA = nw . (pre-scatter slots t-1..t+2) + nw4*admit
        //   wdot = nw . (wt1..wt4)   [hn coefficient picked up by scatter+slide]
        float inp  = tanh_pre(fmaf(xn, we2, be2));
        float ctxA = ((nw[0] * w1 + nw[1] * w2) + (nw[2] * w3 + nw[3] * w4))
                   + nw4 * nf;
        float wdot = (nw[0] * wt1 + nw[1] * wt2) + (nw[2] * wt3 + nw[3] * wt4);
        float base = fmaf(csv, ctxA, inp);
        float coef = fmaf(csv, wdot, 1.f);

        // --- P1: y = W . v via MFMA; D col bn carries row bn&1 ---
        f32x4 a0a = {0,0,0,0}, a0b = {0,0,0,0}, a1a = {0,0,0,0}, a1b = {0,0,0,0};
        #pragma unroll
        for (int kt = 0; kt < 4; ++kt) {
            bf16x8 bfr0 = *(const bf16x8*)(vsrc + kt * 32);
            bf16x8 bfr1 = *(const bf16x8*)(vsrc + (kt + 4) * 32);
            a0a = __builtin_amdgcn_mfma_f32_16x16x32_bf16(wfa[0][kt],     bfr0, a0a, 0, 0, 0);
            a1a = __builtin_amdgcn_mfma_f32_16x16x32_bf16(wfa[1][kt],     bfr0, a1a, 0, 0, 0);
            a0b = __builtin_amdgcn_mfma_f32_16x16x32_bf16(wfa[0][kt + 4], bfr1, a0b, 0, 0, 0);
            a1b = __builtin_amdgcn_mfma_f32_16x16x32_bf16(wfa[1][kt + 4], bfr1, a1b, 0, 0, 0);
        }

        // --- select owned y from regs: (mt,r) = (b>>2, b&3) ---
        f32x4 y0 = a0a + a0b, y1 = a1a + a1b;
        f32x4 ym = (b & 4) ? y1 : y0;
        float yA = (b & 2) ? ym[2] : ym[0];
        float yB = (b & 2) ? ym[3] : ym[1];
        float ysel = (b & 1) ? yB : yA;

        // --- P2: tanh + all-VALU row-parity reduce (bits 1,2,3,4,5) ---
        float yt = tanh_pre(fmaf(ysel, C2, bu2));
        float s1 = yt, s2 = yt * yt;
        s1 = dpp_add<0x4E,  0xf>(s1);  s2 = dpp_add<0x4E,  0xf>(s2);  // xor2
        s1 = dpp_add<0x124, 0xf>(s1);  s2 = dpp_add<0x124, 0xf>(s2);  // ror:4
        s1 = dpp_add<0x128, 0xf>(s1);  s2 = dpp_add<0x128, 0xf>(s2);  // ror:8
        s1 = swap16_add(s1);           s2 = swap16_add(s2);           // bit4
        s1 = swap32_add(s1);           s2 = swap32_add(s2);           // bit5
        // every lane now holds its row's full wave partial.
        // 4 lanes/wave accumulate into s_acc[rb][row][var] (off-chain).
        if (lane < 4)
            atomicAdd(&s_acc[rb * 4 + (lane & 1) * 2 + (lane >> 1)],
                      (lane & 2) ? s2 : s1);
        __syncthreads();   // [1] partials summed (also fences vsrc reads)

        // --- P3: finalize = ONE b64 read; then hn -> v (1 fma + cvt) ---
        f32x2 S = *(const f32x2*)(s_acc + rb * 4 + row * 2);
        if (tid < 4) s_acc[wb * 4 + tid] = 0.f;   // reset other buf (dead now)
        float mu   = S[0] * (1.f / 256.f);
        float var  = S[1] * (1.f / 256.f) - mu * mu;
        float rstd = rsqrtf(var + 1e-5f);
        hn = fmaf(yt - mu, rstd * gm, btt);
        float v = fmaf(coef, hn, base);
        s_v[row * 288 + i_own] = (__bf16)v;        // critical write ASAP

        // --- off-chain: window scatter/slide/retire + prefetches ---
        w0 += wt0 * hn; w1 += wt1 * hn; w2 += wt2 * hn;
        w3 += wt3 * hn; w4 += wt4 * hn;
        mcol[((t - 2) & 63) << 8] = w0;            // retire slot t-2
        w0 = w1; w1 = w2; w2 = w3; w3 = w4; w4 = nf;
        wt0 = nw[0]; wt1 = nw[1]; wt2 = nw[2]; wt3 = nw[3]; wt4 = nw4;
        nf  = mcol[((t + 4) & 63) << 8];           // same-thread col: no hazard
        {   const float* wp = s_wt + ((t + 2) & 63) * 8;
            nw  = *(const f32x4*)wp;
            nw4 = wp[4];
        }
        xn  = s_x[row * 256 + ((t + 2) & 255)];
        __syncthreads();   // [2] v visible
    }

    // --- epilogue: stage hn into s_x (reuse) to restore tid-order ---
    s_x[row * 256 + i_own] = hn;
    __syncthreads();
    {
        const int n = tid >> 8, i = tid & 255;
        float h = s_x[tid];
        #pragma unroll
        for (int o = 0; o < 10; ++o) {
            float p = h * W_out[o * 256 + i];
            #pragma unroll
            for (int m = 32; m >= 1; m >>= 1) p += __shfl_xor(p, m, 64);
            if (lane == 0) atomicAdd(&s_oacc[n * 10 + o], p);
        }
    }
    __syncthreads();
    if (tid < 20) {
        int nn = tid / 10, o = tid % 10;
        out[(r0 + nn) * 10 + o] = s_oacc[tid] + b_out[o];
    }
}

extern "C" void kernel_launch(void* const* d_in, const int* in_sizes, int n_in,
                              void* d_out, int out_size, void* d_ws, size_t ws_size,
                              hipStream_t stream) {
    const float* x    = (const float*)d_in[0];
    const float* W_e  = (const float*)d_in[1];
    const float* b_e  = (const float*)d_in[2];
    const float* W_u  = (const float*)d_in[3];
    const float* b_u  = (const float*)d_in[4];
    const float* gmm  = (const float*)d_in[5];
    const float* bta  = (const float*)d_in[6];
    const float* W_o  = (const float*)d_in[7];
    const float* b_o  = (const float*)d_in[8];
    const float* cst  = (const float*)d_in[9];
    float* out = (float*)d_out;

    (void)hipFuncSetAttribute(reinterpret_cast<const void*>(postnorm_kernel),
                              hipFuncAttributeMaxDynamicSharedMemorySize,
                              SMEM_BYTES);

    postnorm_kernel<<<dim3(256), dim3(512), SMEM_BYTES, stream>>>(
        x, W_e, b_e, W_u, b_u, gmm, bta, W_o, b_o, cst, out);
}